// Round 1
// baseline (1471.643 us; speedup 1.0000x reference)
//
#include <hip/hip_runtime.h>
#include <math.h>

#define H 1024
#define NH 16
#define HD 64

// ---------------------------------------------------------------------------
// GEMM: C[M,N] = A[M,K] @ B[K,N] + bias[N], all row-major fp32.
// 128x128 block tile, 256 threads, 8x8 micro-tile per thread, K-step 16.
// ---------------------------------------------------------------------------
__global__ __launch_bounds__(256) void gemm_bias_kernel(
    const float* __restrict__ A, const float* __restrict__ B,
    const float* __restrict__ bias, float* __restrict__ C,
    int M, int N, int K)
{
    __shared__ float sA[16][132];   // sA[kk][mm], padded: 132*4B row = 16B-aligned
    __shared__ float sB[16][128];   // sB[kk][nn]

    const int tid = threadIdx.x;
    const int tx = tid & 15;        // output col group
    const int ty = tid >> 4;        // output row group
    const int m0 = blockIdx.y * 128;
    const int n0 = blockIdx.x * 128;

    // A-tile load mapping: 128 rows x 16 cols = 512 float4; 2 per thread
    const int arow = tid >> 2;      // 0..63 (and +64)
    const int ac4  = tid & 3;       // float4 col within K-step
    // B-tile load mapping: 16 rows x 128 cols = 512 float4; 2 per thread
    const int brow = tid >> 5;      // 0..7 (and +8)
    const int bc4  = tid & 31;

    const float* Ap = A + (size_t)(m0 + arow) * K + ac4 * 4;
    const float* Bp = B + (size_t)brow * N + n0 + bc4 * 4;

    float acc[8][8];
#pragma unroll
    for (int i = 0; i < 8; i++)
#pragma unroll
        for (int j = 0; j < 8; j++) acc[i][j] = 0.f;

    for (int k0 = 0; k0 < K; k0 += 16) {
        // issue global loads early (overlap with previous tile's compute)
        float4 a0 = *(const float4*)(Ap + k0);
        float4 a1 = *(const float4*)(Ap + (size_t)64 * K + k0);
        float4 b0 = *(const float4*)(Bp + (size_t)k0 * N);
        float4 b1 = *(const float4*)(Bp + (size_t)(k0 + 8) * N);
        __syncthreads();   // previous iteration's readers done
        sA[ac4 * 4 + 0][arow] = a0.x;
        sA[ac4 * 4 + 1][arow] = a0.y;
        sA[ac4 * 4 + 2][arow] = a0.z;
        sA[ac4 * 4 + 3][arow] = a0.w;
        sA[ac4 * 4 + 0][arow + 64] = a1.x;
        sA[ac4 * 4 + 1][arow + 64] = a1.y;
        sA[ac4 * 4 + 2][arow + 64] = a1.z;
        sA[ac4 * 4 + 3][arow + 64] = a1.w;
        *(float4*)&sB[brow][bc4 * 4]     = b0;
        *(float4*)&sB[brow + 8][bc4 * 4] = b1;
        __syncthreads();
#pragma unroll
        for (int kk = 0; kk < 16; kk++) {
            float4 av0 = *(const float4*)&sA[kk][ty * 8];
            float4 av1 = *(const float4*)&sA[kk][ty * 8 + 4];
            float4 bv0 = *(const float4*)&sB[kk][tx * 8];
            float4 bv1 = *(const float4*)&sB[kk][tx * 8 + 4];
            float a[8] = {av0.x, av0.y, av0.z, av0.w, av1.x, av1.y, av1.z, av1.w};
            float b[8] = {bv0.x, bv0.y, bv0.z, bv0.w, bv1.x, bv1.y, bv1.z, bv1.w};
#pragma unroll
            for (int i = 0; i < 8; i++)
#pragma unroll
                for (int j = 0; j < 8; j++)
                    acc[i][j] = fmaf(a[i], b[j], acc[i][j]);
        }
    }

    // epilogue: add bias, vectorized store
    const float* bp = bias + n0 + tx * 8;
    float bsv[8];
#pragma unroll
    for (int j = 0; j < 8; j++) bsv[j] = bp[j];
#pragma unroll
    for (int i = 0; i < 8; i++) {
        float* Cp = C + (size_t)(m0 + ty * 8 + i) * N + n0 + tx * 8;
        float4 r0 = make_float4(acc[i][0] + bsv[0], acc[i][1] + bsv[1],
                                acc[i][2] + bsv[2], acc[i][3] + bsv[3]);
        float4 r1 = make_float4(acc[i][4] + bsv[4], acc[i][5] + bsv[5],
                                acc[i][6] + bsv[6], acc[i][7] + bsv[7]);
        *(float4*)Cp = r0;
        *(float4*)(Cp + 4) = r1;
    }
}

// ---------------------------------------------------------------------------
// Flash attention: one block = one (b, h, 32 q-rows). 256 threads.
// K/V staged in LDS 32 keys at a time; online softmax; mask as -1e30 bias.
// Thread t: qi = t>>3 (q-row in tile), g = t&7.
//   score phase: keys {g, g+8, g+16, g+24} (stride-8 -> conflict-free ks reads)
//   PV phase:    output dims d = g*8..g*8+7
// ---------------------------------------------------------------------------
__global__ __launch_bounds__(256) void attn_kernel(
    const float* __restrict__ qws,   // [B][Sq][H]
    const float* __restrict__ kws,   // [B][Sk][H]
    const float* __restrict__ vws,   // [B][Sk][H]
    const int*   __restrict__ mask,  // [B][Sk]
    float* __restrict__ ctx,         // [B][Sq][H]
    int Sq, int Sk)
{
    const int b  = blockIdx.z;
    const int h  = blockIdx.y;
    const int q0 = blockIdx.x * 32;
    const int tid = threadIdx.x;
    const int qi = tid >> 3;   // 0..31
    const int g  = tid & 7;    // 0..7

    __shared__ float qs[32][68];
    __shared__ float ks[32][68];
    __shared__ float vs[32][68];
    __shared__ float ps[32][36];
    __shared__ float sbias[32];

    const float* qbase = qws + ((size_t)b * Sq + q0) * H + h * HD;
    const float* kbase = kws + (size_t)b * Sk * H + h * HD;
    const float* vbase = vws + (size_t)b * Sk * H + h * HD;
    const int*   mb    = mask + b * Sk;

    {   // load q tile: row = tid>>3, d = (tid&7)*8
        const int row = qi, d = g * 8;
        const float* p = qbase + (size_t)row * H + d;
        *(float4*)&qs[row][d]     = *(const float4*)p;
        *(float4*)&qs[row][d + 4] = *(const float4*)(p + 4);
    }

    float o[8];
#pragma unroll
    for (int i = 0; i < 8; i++) o[i] = 0.f;
    float m = -1e30f, l = 0.f;

    for (int kt = 0; kt < Sk; kt += 32) {
        __syncthreads();   // previous tile's PV reads done (also covers q store)
        {
            const int row = qi, d = g * 8;
            const float* pk = kbase + (size_t)(kt + row) * H + d;
            *(float4*)&ks[row][d]     = *(const float4*)pk;
            *(float4*)&ks[row][d + 4] = *(const float4*)(pk + 4);
            const float* pv = vbase + (size_t)(kt + row) * H + d;
            *(float4*)&vs[row][d]     = *(const float4*)pv;
            *(float4*)&vs[row][d + 4] = *(const float4*)(pv + 4);
            if (tid < 32) sbias[tid] = mb[kt + tid] ? 0.f : -1e30f;
        }
        __syncthreads();

        // ---- scores for keys g+8j
        float s[4];
#pragma unroll
        for (int j = 0; j < 4; j++) s[j] = 0.f;
#pragma unroll
        for (int d4 = 0; d4 < 16; d4++) {
            float4 qv = *(const float4*)&qs[qi][d4 * 4];
#pragma unroll
            for (int j = 0; j < 4; j++) {
                float4 kv = *(const float4*)&ks[g + 8 * j][d4 * 4];
                s[j] = fmaf(qv.x, kv.x, s[j]);
                s[j] = fmaf(qv.y, kv.y, s[j]);
                s[j] = fmaf(qv.z, kv.z, s[j]);
                s[j] = fmaf(qv.w, kv.w, s[j]);
            }
        }
        float tmax = -1e30f;
#pragma unroll
        for (int j = 0; j < 4; j++) {
            s[j] = s[j] * 0.125f + sbias[g + 8 * j];
            tmax = fmaxf(tmax, s[j]);
        }
#pragma unroll
        for (int w = 1; w < 8; w <<= 1)
            tmax = fmaxf(tmax, __shfl_xor(tmax, w, 64));

        const float mnew  = fmaxf(m, tmax);
        const float scale = __expf(m - mnew);
        float tsum = 0.f;
#pragma unroll
        for (int j = 0; j < 4; j++) {
            s[j] = __expf(s[j] - mnew);
            tsum += s[j];
        }
#pragma unroll
        for (int w = 1; w < 8; w <<= 1)
            tsum += __shfl_xor(tsum, w, 64);
        l = l * scale + tsum;
        m = mnew;
#pragma unroll
        for (int j = 0; j < 4; j++) ps[qi][g + 8 * j] = s[j];
        __syncthreads();

        // ---- PV: o[d] for d = g*8..g*8+7
#pragma unroll
        for (int i = 0; i < 8; i++) o[i] *= scale;
#pragma unroll
        for (int kk = 0; kk < 32; kk++) {
            const float p = ps[qi][kk];
            float4 v0 = *(const float4*)&vs[kk][g * 8];
            float4 v1 = *(const float4*)&vs[kk][g * 8 + 4];
            o[0] = fmaf(p, v0.x, o[0]);
            o[1] = fmaf(p, v0.y, o[1]);
            o[2] = fmaf(p, v0.z, o[2]);
            o[3] = fmaf(p, v0.w, o[3]);
            o[4] = fmaf(p, v1.x, o[4]);
            o[5] = fmaf(p, v1.y, o[5]);
            o[6] = fmaf(p, v1.z, o[6]);
            o[7] = fmaf(p, v1.w, o[7]);
        }
    }

    const float inv = 1.f / l;
    float* outp = ctx + ((size_t)b * Sq + q0 + qi) * H + h * HD + g * 8;
    float4 r0 = make_float4(o[0] * inv, o[1] * inv, o[2] * inv, o[3] * inv);
    float4 r1 = make_float4(o[4] * inv, o[5] * inv, o[6] * inv, o[7] * inv);
    *(float4*)outp       = r0;
    *(float4*)(outp + 4) = r1;
}

// ---------------------------------------------------------------------------
extern "C" void kernel_launch(void* const* d_in, const int* in_sizes, int n_in,
                              void* d_out, int out_size, void* d_ws, size_t ws_size,
                              hipStream_t stream) {
    const float* query = (const float*)d_in[0];   // [4,1024,1024]
    const float* key   = (const float*)d_in[1];   // [4,2048,1024]
    const float* value = (const float*)d_in[2];   // [4,2048,1024]
    const int*   mask  = (const int*)d_in[3];     // [4,2048]
    const float* Wq = (const float*)d_in[4];
    const float* bq = (const float*)d_in[5];
    const float* Wk = (const float*)d_in[6];
    const float* bk = (const float*)d_in[7];
    const float* Wv = (const float*)d_in[8];
    const float* bv = (const float*)d_in[9];
    const float* Wo = (const float*)d_in[10];
    const float* bo = (const float*)d_in[11];
    float* out = (float*)d_out;

    const int B  = 4;
    const int Sq = 1024;
    const int Sk = 2048;

    float* qws = (float*)d_ws;                         //  4M floats
    float* kws = qws + (size_t)B * Sq * H;             //  8M floats
    float* vws = kws + (size_t)B * Sk * H;             //  8M floats
    float* cws = vws + (size_t)B * Sk * H;             //  4M floats

    dim3 blk(256);
    // projections
    gemm_bias_kernel<<<dim3(H / 128, (B * Sq) / 128), blk, 0, stream>>>(
        query, Wq, bq, qws, B * Sq, H, H);
    gemm_bias_kernel<<<dim3(H / 128, (B * Sk) / 128), blk, 0, stream>>>(
        key, Wk, bk, kws, B * Sk, H, H);
    gemm_bias_kernel<<<dim3(H / 128, (B * Sk) / 128), blk, 0, stream>>>(
        value, Wv, bv, vws, B * Sk, H, H);
    // fused masked softmax attention
    attn_kernel<<<dim3(Sq / 32, NH, B), blk, 0, stream>>>(
        qws, kws, vws, mask, cws, Sq, Sk);
    // output projection
    gemm_bias_kernel<<<dim3(H / 128, (B * Sq) / 128), blk, 0, stream>>>(
        cws, Wo, bo, out, B * Sq, H, H);
}

// Round 2
// 244.042 us; speedup vs baseline: 6.0303x; 6.0303x over previous
//
#include <hip/hip_runtime.h>
#include <hip/hip_fp16.h>
#include <math.h>

#define B_ 4
#define SQ 1024
#define SK 2048
#define HH 1024
#define NHEAD 16
#define HDIM 64

typedef _Float16 f16;
typedef __attribute__((ext_vector_type(8))) _Float16 f16x8;
typedef __attribute__((ext_vector_type(4))) _Float16 f16x4;
typedef __attribute__((ext_vector_type(4))) float f32x4;
typedef unsigned int u32;

#define GLOAD_LDS16(gp, lp) __builtin_amdgcn_global_load_lds( \
    (const __attribute__((address_space(1))) u32*)(gp),        \
    (__attribute__((address_space(3))) u32*)(lp), 16, 0, 0)

// ---------------------------------------------------------------------------
// fp32 -> f16 elementwise cast, 8 elems/thread
// ---------------------------------------------------------------------------
__global__ __launch_bounds__(256) void cast_f32_f16_k(const float* __restrict__ in,
                                                      f16* __restrict__ out, int n8) {
    int i = blockIdx.x * 256 + threadIdx.x;
    if (i >= n8) return;
    const float4* ip = (const float4*)in;
    float4 a = ip[(size_t)i * 2];
    float4 b = ip[(size_t)i * 2 + 1];
    f16x8 v;
    v[0] = (f16)a.x; v[1] = (f16)a.y; v[2] = (f16)a.z; v[3] = (f16)a.w;
    v[4] = (f16)b.x; v[5] = (f16)b.y; v[6] = (f16)b.z; v[7] = (f16)b.w;
    *(f16x8*)(out + (size_t)i * 8) = v;
}

// ---------------------------------------------------------------------------
// W [1024][1024] f32 -> WT [1024][1024] f16, WT[n][k] = W[k][n]. 64x64 tiles.
// ---------------------------------------------------------------------------
__global__ __launch_bounds__(256) void transW_k(const float* __restrict__ W,
                                                f16* __restrict__ WT) {
    __shared__ f16 t[64 * 80];
    const int r0 = blockIdx.y * 64, c0 = blockIdx.x * 64, tid = threadIdx.x;
#pragma unroll
    for (int p = 0; p < 4; p++) {
        int s = p * 256 + tid;
        int row = s >> 4, u = s & 15;
        float4 a = *(const float4*)(W + (size_t)(r0 + row) * HH + c0 + u * 4);
        f16x4 v;
        v[0] = (f16)a.x; v[1] = (f16)a.y; v[2] = (f16)a.z; v[3] = (f16)a.w;
        *(f16x4*)(t + row * 80 + u * 4) = v;
    }
    __syncthreads();
#pragma unroll
    for (int p = 0; p < 2; p++) {
        int s = p * 256 + tid;
        int n = s >> 3, u = s & 7;
        f16x8 v;
#pragma unroll
        for (int j = 0; j < 8; j++) v[j] = t[(u * 8 + j) * 80 + n];
        *(f16x8*)(WT + (size_t)(c0 + n) * HH + r0 + u * 8) = v;
    }
}

// ---------------------------------------------------------------------------
// vtmp [B][SK][H] f16 -> vt [B*NH][HD][SK] f16 (per-head transpose)
// ---------------------------------------------------------------------------
__global__ __launch_bounds__(256) void transV_k(const f16* __restrict__ vtmp,
                                                f16* __restrict__ vt) {
    __shared__ f16 t[64 * 80];
    const int k0 = blockIdx.x * 64, h = blockIdx.y, b = blockIdx.z, tid = threadIdx.x;
    const f16* ip = vtmp + ((size_t)(b * SK + k0)) * HH + h * HDIM;
#pragma unroll
    for (int p = 0; p < 2; p++) {
        int s = p * 256 + tid;
        int key = s >> 3, u = s & 7;
        f16x8 v = *(const f16x8*)(ip + (size_t)key * HH + u * 8);
        *(f16x8*)(t + key * 80 + u * 8) = v;
    }
    __syncthreads();
    f16* op = vt + ((size_t)(b * NHEAD + h)) * HDIM * SK + k0;
#pragma unroll
    for (int p = 0; p < 2; p++) {
        int s = p * 256 + tid;
        int d = s >> 3, u = s & 7;
        f16x8 v;
#pragma unroll
        for (int j = 0; j < 8; j++) v[j] = t[(u * 8 + j) * 80 + d];
        *(f16x8*)(op + (size_t)d * SK + u * 8) = v;
    }
}

// ---------------------------------------------------------------------------
// GEMM C[M,N] = A[M,K] (f16) @ BT[N,K]^T (f16) + bias (f32).
// 128x128 tile, BK=32, 4 waves 2x2, 16 MFMA + 8 ds_read_b128 per K-step.
// OUTF16: 1 -> f16 out, 0 -> f32 out.
// ---------------------------------------------------------------------------
template <int OUTF16>
__global__ __launch_bounds__(256) void gemm_f16_k(
    const f16* __restrict__ A, const f16* __restrict__ BT,
    const float* __restrict__ bias, void* __restrict__ Cout,
    int M, int N, int K)
{
    __shared__ f16 sA[128 * 32];
    __shared__ f16 sB[128 * 32];
    const int tid = threadIdx.x, lane = tid & 63, wid = tid >> 6;
    const int m0 = blockIdx.y * 128, n0 = blockIdx.x * 128;
    const int wr = wid >> 1, wc = wid & 1;
    const int ql = lane & 15, g = lane >> 4;
    f32x4 acc[4][4] = {};

    for (int k0 = 0; k0 < K; k0 += 32) {
        __syncthreads();
#pragma unroll
        for (int p = 0; p < 2; p++) {
            int s = p * 256 + tid;
            int row = s >> 2, u = s & 3;
            GLOAD_LDS16(A  + (size_t)(m0 + row) * K + k0 + u * 8,
                        sA + (size_t)(p * 256 + wid * 64) * 8);
            GLOAD_LDS16(BT + (size_t)(n0 + row) * K + k0 + u * 8,
                        sB + (size_t)(p * 256 + wid * 64) * 8);
        }
        __syncthreads();
        f16x8 af[4], bf[4];
#pragma unroll
        for (int m = 0; m < 4; m++)
            af[m] = *(const f16x8*)(sA + (wr * 64 + m * 16 + ql) * 32 + g * 8);
#pragma unroll
        for (int n = 0; n < 4; n++)
            bf[n] = *(const f16x8*)(sB + (wc * 64 + n * 16 + ql) * 32 + g * 8);
#pragma unroll
        for (int m = 0; m < 4; m++)
#pragma unroll
            for (int n = 0; n < 4; n++)
                acc[m][n] = __builtin_amdgcn_mfma_f32_16x16x32_f16(af[m], bf[n], acc[m][n], 0, 0, 0);
    }

    float bv[4];
#pragma unroll
    for (int n = 0; n < 4; n++) bv[n] = bias[n0 + wc * 64 + n * 16 + ql];
#pragma unroll
    for (int m = 0; m < 4; m++) {
        int row0 = m0 + wr * 64 + m * 16 + g * 4;
#pragma unroll
        for (int n = 0; n < 4; n++) {
            int col = n0 + wc * 64 + n * 16 + ql;
#pragma unroll
            for (int e = 0; e < 4; e++) {
                float v = acc[m][n][e] + bv[n];
                if (OUTF16) ((f16*)Cout)[(size_t)(row0 + e) * N + col] = (f16)v;
                else        ((float*)Cout)[(size_t)(row0 + e) * N + col] = v;
            }
        }
    }
}

// ---------------------------------------------------------------------------
// Flash attention, f16 MFMA. Block = 4 waves x 16 q-rows = 64 q-rows, one (b,h).
// Swapped QK^T: sacc = mfma(K_frag, Q_frag) -> S^T; per-lane q = lane&15.
// K/V^T staged via global_load_lds with XOR-swizzled source (conflict-free reads).
// P -> per-wave padded LDS -> A-frags for PV.
// ---------------------------------------------------------------------------
__global__ __launch_bounds__(256) void attn_mfma_k(
    const f16* __restrict__ qp,   // [B][SQ][H]
    const f16* __restrict__ kp,   // [B][SK][H]
    const f16* __restrict__ vt,   // [B*NH][HD][SK]
    const int* __restrict__ mask, // [B][SK]
    f16* __restrict__ ctx)        // [B][SQ][H]
{
    const int b = blockIdx.z, h = blockIdx.y, q0 = blockIdx.x * 64;
    const int tid = threadIdx.x, lane = tid & 63, w = tid >> 6;
    const int ql = lane & 15, g = lane >> 4;

    __shared__ f16 ks[64 * 64];        // [key][d] 16B-unit swizzled: u_phys = u ^ (key&7)
    __shared__ f16 vs[64 * 64];        // [d][k]   16B-unit swizzled: u_phys = u ^ (d&7)
    __shared__ f16 plds[4][16 * 80];   // per-wave P [q16][key64+pad]
    __shared__ float sbias[64];

    f16x8 qf[2];
    {
        const f16* qb = qp + ((size_t)(b * SQ + q0 + w * 16 + ql)) * HH + h * HDIM + g * 8;
        qf[0] = *(const f16x8*)qb;
        qf[1] = *(const f16x8*)(qb + 32);
    }
    f32x4 oacc[4] = {};
    float mrun = -1e30f, lrun = 0.f;
    const int* mb = mask + b * SK;
    const f16* kbase = kp + (size_t)b * SK * HH + h * HDIM;
    const f16* vbase = vt + ((size_t)(b * NHEAD + h)) * HDIM * SK;

    for (int kt = 0; kt < SK; kt += 64) {
        __syncthreads();
        {
            int s = w * 64 + lane;
            int r = s >> 3, u = s & 7, ulg = u ^ (r & 7);
            GLOAD_LDS16(kbase + (size_t)(kt + r) * HH + ulg * 8, ks + (size_t)w * 512);
            GLOAD_LDS16(vbase + (size_t)r * SK + kt + ulg * 8,   vs + (size_t)w * 512);
            int s2 = 256 + s;
            int r2 = s2 >> 3, u2 = s2 & 7, ulg2 = u2 ^ (r2 & 7);
            GLOAD_LDS16(kbase + (size_t)(kt + r2) * HH + ulg2 * 8, ks + 2048 + (size_t)w * 512);
            GLOAD_LDS16(vbase + (size_t)r2 * SK + kt + ulg2 * 8,   vs + 2048 + (size_t)w * 512);
            if (tid < 64) sbias[tid] = mb[kt + tid] ? 0.f : -1e30f;
        }
        __syncthreads();

        // S^T = K . Q^T : sacc[n][e] = S[q=ql][key = n*16 + g*4 + e]
        f32x4 sacc[4] = {};
#pragma unroll
        for (int n = 0; n < 4; n++) {
            int key = n * 16 + ql;
#pragma unroll
            for (int df = 0; df < 2; df++) {
                int u = df * 4 + g;
                f16x8 kf = *(const f16x8*)(ks + key * 64 + ((u ^ (key & 7)) * 8));
                sacc[n] = __builtin_amdgcn_mfma_f32_16x16x32_f16(kf, qf[df], sacc[n], 0, 0, 0);
            }
        }

        // online softmax over this tile's 64 keys (per q = ql)
        float sv[4][4];
        float mt = -1e30f;
#pragma unroll
        for (int n = 0; n < 4; n++)
#pragma unroll
            for (int e = 0; e < 4; e++) {
                float s = sacc[n][e] * 0.125f + sbias[n * 16 + g * 4 + e];
                sv[n][e] = s;
                mt = fmaxf(mt, s);
            }
        mt = fmaxf(mt, __shfl_xor(mt, 16, 64));
        mt = fmaxf(mt, __shfl_xor(mt, 32, 64));
        float mnew = fmaxf(mrun, mt);
        float alpha = __expf(mrun - mnew);
        mrun = mnew;
        float tsum = 0.f;
        f16x4 pk[4];
#pragma unroll
        for (int n = 0; n < 4; n++) {
            float p0 = __expf(sv[n][0] - mnew), p1 = __expf(sv[n][1] - mnew);
            float p2 = __expf(sv[n][2] - mnew), p3 = __expf(sv[n][3] - mnew);
            tsum += (p0 + p1) + (p2 + p3);
            f16x4 pv4;
            pv4[0] = (f16)p0; pv4[1] = (f16)p1; pv4[2] = (f16)p2; pv4[3] = (f16)p3;
            pk[n] = pv4;
        }
        tsum += __shfl_xor(tsum, 16, 64);
        tsum += __shfl_xor(tsum, 32, 64);
        lrun = lrun * alpha + tsum;

        // write P row-major into per-wave LDS: plds[q=ql][key]
#pragma unroll
        for (int n = 0; n < 4; n++)
            *(f16x4*)(plds[w] + ql * 80 + n * 16 + g * 4) = pk[n];

        // rescale O by alpha of row q' = g*4+e
        float al[4];
#pragma unroll
        for (int e = 0; e < 4; e++) al[e] = __shfl(alpha, g * 4 + e, 64);
#pragma unroll
        for (int df = 0; df < 4; df++)
#pragma unroll
            for (int e = 0; e < 4; e++) oacc[df][e] *= al[e];

        // O += P . V  (A-frags from plds, B-frags from swizzled vs)
#pragma unroll
        for (int t = 0; t < 2; t++) {
            f16x8 pf = *(const f16x8*)(plds[w] + ql * 80 + t * 32 + g * 8);
#pragma unroll
            for (int df = 0; df < 4; df++) {
                int d = df * 16 + ql;
                int u = t * 4 + g;
                f16x8 vf = *(const f16x8*)(vs + d * 64 + ((u ^ (d & 7)) * 8));
                oacc[df] = __builtin_amdgcn_mfma_f32_16x16x32_f16(pf, vf, oacc[df], 0, 0, 0);
            }
        }
    }

    float linv[4];
#pragma unroll
    for (int e = 0; e < 4; e++) {
        float lv = __shfl(lrun, g * 4 + e, 64);
        linv[e] = 1.f / lv;
    }
    f16* ob = ctx + ((size_t)(b * SQ + q0 + w * 16)) * HH + h * HDIM;
#pragma unroll
    for (int df = 0; df < 4; df++)
#pragma unroll
        for (int e = 0; e < 4; e++)
            ob[(size_t)(g * 4 + e) * HH + df * 16 + ql] = (f16)(oacc[df][e] * linv[e]);
}

// ---------------------------------------------------------------------------
extern "C" void kernel_launch(void* const* d_in, const int* in_sizes, int n_in,
                              void* d_out, int out_size, void* d_ws, size_t ws_size,
                              hipStream_t stream) {
    const float* query = (const float*)d_in[0];
    const float* key   = (const float*)d_in[1];
    const float* value = (const float*)d_in[2];
    const int*   mask  = (const int*)d_in[3];
    const float* Wq = (const float*)d_in[4];
    const float* bq = (const float*)d_in[5];
    const float* Wk = (const float*)d_in[6];
    const float* bk = (const float*)d_in[7];
    const float* Wv = (const float*)d_in[8];
    const float* bv = (const float*)d_in[9];
    const float* Wo = (const float*)d_in[10];
    const float* bo = (const float*)d_in[11];
    float* out = (float*)d_out;

    // workspace layout (f16 units), 44M f16 = 88 MB
    const size_t M1 = 1024 * 1024;
    f16* qcast = (f16*)d_ws;            // 4M  [ctx aliases this later]
    f16* kcast = qcast + 4 * M1;        // 8M
    f16* vcast = kcast + 8 * M1;        // 8M  [vt aliases this later]
    f16* wT    = vcast + 8 * M1;        // 4 x 1M
    f16* qp    = wT + 4 * M1;           // 4M
    f16* kp    = qp + 4 * M1;           // 8M
    f16* vtmp  = kp + 8 * M1;           // 8M
    f16* vt    = vcast;                 // alias (vcast dead after V-GEMM)
    f16* ctx   = qcast;                 // alias (qcast dead after Q-GEMM)

    dim3 blk(256);

    // casts
    cast_f32_f16_k<<<dim3(2048), blk, 0, stream>>>(query, qcast, 4 * M1 / 8);
    cast_f32_f16_k<<<dim3(4096), blk, 0, stream>>>(key,   kcast, 8 * M1 / 8);
    cast_f32_f16_k<<<dim3(4096), blk, 0, stream>>>(value, vcast, 8 * M1 / 8);
    // weight transposes (f32 -> f16, [k][n] -> [n][k])
    transW_k<<<dim3(16, 16), blk, 0, stream>>>(Wq, wT + 0 * M1);
    transW_k<<<dim3(16, 16), blk, 0, stream>>>(Wk, wT + 1 * M1);
    transW_k<<<dim3(16, 16), blk, 0, stream>>>(Wv, wT + 2 * M1);
    transW_k<<<dim3(16, 16), blk, 0, stream>>>(Wo, wT + 3 * M1);

    // projections
    gemm_f16_k<1><<<dim3(8, 32), blk, 0, stream>>>(qcast, wT + 0 * M1, bq, qp,   4096, HH, HH);
    gemm_f16_k<1><<<dim3(8, 64), blk, 0, stream>>>(kcast, wT + 1 * M1, bk, kp,   8192, HH, HH);
    gemm_f16_k<1><<<dim3(8, 64), blk, 0, stream>>>(vcast, wT + 2 * M1, bv, vtmp, 8192, HH, HH);
    // V per-head transpose
    transV_k<<<dim3(32, 16, 4), blk, 0, stream>>>(vtmp, vt);
    // fused attention
    attn_mfma_k<<<dim3(16, 16, 4), blk, 0, stream>>>(qp, kp, vt, mask, ctx);
    // output projection (f32 out)
    gemm_f16_k<0><<<dim3(8, 32), blk, 0, stream>>>(ctx, wT + 3 * M1, bo, out, 4096, HH, HH);
}

// Round 3
// 224.048 us; speedup vs baseline: 6.5684x; 1.0892x over previous
//
#include <hip/hip_runtime.h>
#include <hip/hip_fp16.h>
#include <math.h>

#define B_ 4
#define SQ 1024
#define SK 2048
#define HH 1024
#define NHEAD 16
#define HDIM 64

typedef _Float16 f16;
typedef __attribute__((ext_vector_type(8))) _Float16 f16x8;
typedef __attribute__((ext_vector_type(4))) _Float16 f16x4;
typedef __attribute__((ext_vector_type(4))) float f32x4;
typedef unsigned int u32;

#define GLOAD_LDS16(gp, lp) __builtin_amdgcn_global_load_lds( \
    (const __attribute__((address_space(1))) u32*)(gp),        \
    (__attribute__((address_space(3))) u32*)(lp), 16, 0, 0)

// ---------------------------------------------------------------------------
// fused fp32 -> f16 cast for q, k, v. 8 elems/thread.
// groups: q 524288, k 1048576, v 1048576 (total 2621440 -> grid 10240)
// ---------------------------------------------------------------------------
__global__ __launch_bounds__(256) void cast3_k(
    const float* __restrict__ q, const float* __restrict__ k,
    const float* __restrict__ v, f16* __restrict__ qo,
    f16* __restrict__ ko, f16* __restrict__ vo) {
    int i = blockIdx.x * 256 + threadIdx.x;
    const float* src; f16* dst; int j;
    if (i < 524288)       { src = q; dst = qo; j = i; }
    else if (i < 1572864) { src = k; dst = ko; j = i - 524288; }
    else                  { src = v; dst = vo; j = i - 1572864; }
    float4 a = ((const float4*)src)[(size_t)j * 2];
    float4 b = ((const float4*)src)[(size_t)j * 2 + 1];
    f16x8 o;
    o[0] = (f16)a.x; o[1] = (f16)a.y; o[2] = (f16)a.z; o[3] = (f16)a.w;
    o[4] = (f16)b.x; o[5] = (f16)b.y; o[6] = (f16)b.z; o[7] = (f16)b.w;
    *(f16x8*)(dst + (size_t)j * 8) = o;
}

// ---------------------------------------------------------------------------
// 4x W [1024][1024] f32 -> WT f16 transposed; blockIdx.z selects matrix.
// ---------------------------------------------------------------------------
__global__ __launch_bounds__(256) void transW4_k(
    const float* __restrict__ W0, const float* __restrict__ W1,
    const float* __restrict__ W2, const float* __restrict__ W3,
    f16* __restrict__ WT) {
    const float* W = blockIdx.z == 0 ? W0 : blockIdx.z == 1 ? W1
                   : blockIdx.z == 2 ? W2 : W3;
    f16* out = WT + (size_t)blockIdx.z * HH * HH;
    __shared__ f16 t[64 * 80];
    const int r0 = blockIdx.y * 64, c0 = blockIdx.x * 64, tid = threadIdx.x;
#pragma unroll
    for (int p = 0; p < 4; p++) {
        int s = p * 256 + tid;
        int row = s >> 4, u = s & 15;
        float4 a = *(const float4*)(W + (size_t)(r0 + row) * HH + c0 + u * 4);
        f16x4 v;
        v[0] = (f16)a.x; v[1] = (f16)a.y; v[2] = (f16)a.z; v[3] = (f16)a.w;
        *(f16x4*)(t + row * 80 + u * 4) = v;
    }
    __syncthreads();
#pragma unroll
    for (int p = 0; p < 2; p++) {
        int s = p * 256 + tid;
        int n = s >> 3, u = s & 7;
        f16x8 v;
#pragma unroll
        for (int j = 0; j < 8; j++) v[j] = t[(u * 8 + j) * 80 + n];
        *(f16x8*)(out + (size_t)(c0 + n) * HH + r0 + u * 8) = v;
    }
}

// ---------------------------------------------------------------------------
// GEMM C = A[M,K] @ BT[N,K]^T + bias. N = 1024 (gridN = 8). Tile 64x128,
// BK=32, 4 waves (2x2), 8 MFMA + 6 ds_read_b128 per K-step. XCD swizzle.
// OUTMODE: 0 f32 row-major; 1 f16 row-major; 2 f16 V^T [B*NH][HD][SK].
// ---------------------------------------------------------------------------
template <int OUTMODE>
__global__ __launch_bounds__(256) void gemm_k(
    const f16* __restrict__ A, const f16* __restrict__ BT,
    const float* __restrict__ bias, void* __restrict__ Cout,
    int M, int K)
{
    __shared__ f16 sA[64 * 32];
    __shared__ f16 sB[128 * 32];
    const int tid = threadIdx.x, lane = tid & 63, w = tid >> 6;
    const int bid = blockIdx.x, nwg = gridDim.x;
    const int swz = (bid & 7) * (nwg >> 3) + (bid >> 3);
    const int m0 = (swz >> 3) * 64;
    const int n0 = (swz & 7) * 128;
    const int wr = w >> 1, wc = w & 1;
    const int ql = lane & 15, g = lane >> 4;
    const int N = 1024;
    f32x4 acc[2][4] = {};

    for (int k0 = 0; k0 < K; k0 += 32) {
        __syncthreads();
        {
            int row = tid >> 2, u = (tid & 3) * 8;
            GLOAD_LDS16(A  + (size_t)(m0 + row) * K + k0 + u, sA + w * 512);
            GLOAD_LDS16(BT + (size_t)(n0 + row) * K + k0 + u, sB + w * 512);
            int s2 = tid + 256, row2 = s2 >> 2, u2 = (s2 & 3) * 8;
            GLOAD_LDS16(BT + (size_t)(n0 + row2) * K + k0 + u2, sB + 2048 + w * 512);
        }
        __syncthreads();
        f16x8 af[2], bf[4];
#pragma unroll
        for (int m = 0; m < 2; m++)
            af[m] = *(const f16x8*)(sA + (wr * 32 + m * 16 + ql) * 32 + g * 8);
#pragma unroll
        for (int n = 0; n < 4; n++)
            bf[n] = *(const f16x8*)(sB + (wc * 64 + n * 16 + ql) * 32 + g * 8);
#pragma unroll
        for (int m = 0; m < 2; m++)
#pragma unroll
            for (int n = 0; n < 4; n++)
                acc[m][n] = __builtin_amdgcn_mfma_f32_16x16x32_f16(af[m], bf[n], acc[m][n], 0, 0, 0);
    }

    float bv[4];
#pragma unroll
    for (int n = 0; n < 4; n++) bv[n] = bias[n0 + wc * 64 + n * 16 + ql];
#pragma unroll
    for (int m = 0; m < 2; m++) {
        int row0 = m0 + wr * 32 + m * 16 + g * 4;
#pragma unroll
        for (int n = 0; n < 4; n++) {
            int col = n0 + wc * 64 + n * 16 + ql;
            if (OUTMODE == 2) {
                int bb = row0 >> 11, kk = row0 & 2047;
                int hh = col >> 6, dd = col & 63;
                f16x4 vv;
#pragma unroll
                for (int e = 0; e < 4; e++) vv[e] = (f16)(acc[m][n][e] + bv[n]);
                *(f16x4*)((f16*)Cout + ((size_t)(bb * NHEAD + hh) * HDIM + dd) * SK + kk) = vv;
            } else if (OUTMODE == 1) {
#pragma unroll
                for (int e = 0; e < 4; e++)
                    ((f16*)Cout)[(size_t)(row0 + e) * N + col] = (f16)(acc[m][n][e] + bv[n]);
            } else {
#pragma unroll
                for (int e = 0; e < 4; e++)
                    ((float*)Cout)[(size_t)(row0 + e) * N + col] = acc[m][n][e] + bv[n];
            }
        }
    }
}

// ---------------------------------------------------------------------------
// Flash attention, f16 MFMA, double-buffered K/V staging (1 barrier/tile),
// log2-domain online softmax with defer-max, XCD-swizzled block order.
// Block = 4 waves x 16 q-rows = 64 q-rows of one (b,h). KVBLK = 64.
// ---------------------------------------------------------------------------
#define SC2 0.18033688f   /* 0.125 * log2(e) */
#define THR2 11.5f

__global__ __launch_bounds__(256) void attn_mfma_k(
    const f16* __restrict__ qp,   // [B][SQ][H]
    const f16* __restrict__ kp,   // [B][SK][H]
    const f16* __restrict__ vt,   // [B*NH][HD][SK]
    const int* __restrict__ mask, // [B][SK]
    f16* __restrict__ ctx)        // [B][SQ][H]
{
    // XCD swizzle: 128 consecutive flat ids (8 full (b,h) K/V sets = 4MB) per XCD
    const int flat = (blockIdx.x & 7) * 128 + (blockIdx.x >> 3);
    const int qt = flat & 15, h = (flat >> 4) & 15, b = flat >> 8;
    const int q0 = qt * 64;
    const int tid = threadIdx.x, lane = tid & 63, w = tid >> 6;
    const int ql = lane & 15, g = lane >> 4;

    __shared__ f16 ks[2 * 4096];      // [buf][key64][d64] 16B-unit swizzle u^(key&7)
    __shared__ f16 vs[2 * 4096];      // [buf][d64][key64] 16B-unit swizzle u^(d&7)
    __shared__ f16 plds[4][16 * 80];  // per-wave P [q16][key64 + pad]
    __shared__ float sball[SK];       // log2-domain mask bias for all keys

    const int* mb = mask + b * SK;
    const f16* kbase = kp + (size_t)b * SK * HH + h * HDIM;
    const f16* vbase = vt + ((size_t)(b * NHEAD + h)) * HDIM * SK;

    f16x8 qf[2];
    {
        const f16* qb = qp + ((size_t)(b * SQ + q0 + w * 16 + ql)) * HH + h * HDIM + g * 8;
        qf[0] = *(const f16x8*)qb;
        qf[1] = *(const f16x8*)(qb + 32);
    }
#pragma unroll
    for (int s = 0; s < 8; s++) {
        int i = s * 256 + tid;
        sball[i] = mb[i] ? 0.f : -1e30f;
    }

    auto stageKV = [&](int buf, int kt) {
        f16* kd = ks + buf * 4096 + w * 512;
        f16* vd = vs + buf * 4096 + w * 512;
        int s = w * 64 + lane;
        int r = s >> 3, ulg = ((s & 7) ^ (r & 7)) * 8;
        GLOAD_LDS16(kbase + (size_t)(kt + r) * HH + ulg, kd);
        GLOAD_LDS16(vbase + (size_t)r * SK + kt + ulg, vd);
        int s2 = s + 256;
        int r2 = s2 >> 3, ulg2 = ((s2 & 7) ^ (r2 & 7)) * 8;
        GLOAD_LDS16(kbase + (size_t)(kt + r2) * HH + ulg2, kd + 2048);
        GLOAD_LDS16(vbase + (size_t)r2 * SK + kt + ulg2, vd + 2048);
    };

    f32x4 oacc[4] = {};
    float mrun = -1e30f, lrun = 0.f;

    stageKV(0, 0);
    int cur = 0;
    for (int kt = 0; kt < SK; kt += 64) {
        __syncthreads();                       // buf[cur] staged; prior reads done
        if (kt + 64 < SK) stageKV(cur ^ 1, kt + 64);
        const f16* kb = ks + cur * 4096;
        const f16* vb = vs + cur * 4096;

        // S^T = K . Q^T : sacc[n][e] = S[q=ql][key = n*16 + g*4 + e]
        f32x4 sacc[4] = {};
        __builtin_amdgcn_s_setprio(1);
#pragma unroll
        for (int n = 0; n < 4; n++) {
            int key = n * 16 + ql;
#pragma unroll
            for (int df = 0; df < 2; df++) {
                int u = df * 4 + g;
                f16x8 kf = *(const f16x8*)(kb + key * 64 + ((u ^ (key & 7)) * 8));
                sacc[n] = __builtin_amdgcn_mfma_f32_16x16x32_f16(kf, qf[df], sacc[n], 0, 0, 0);
            }
        }
        __builtin_amdgcn_s_setprio(0);

        // log2-domain online softmax
        float sv[4][4];
        float mt = -1e30f;
#pragma unroll
        for (int n = 0; n < 4; n++)
#pragma unroll
            for (int e = 0; e < 4; e++) {
                float s = sacc[n][e] * SC2 + sball[kt + n * 16 + g * 4 + e];
                sv[n][e] = s;
                mt = fmaxf(mt, s);
            }
        mt = fmaxf(mt, __shfl_xor(mt, 16, 64));
        mt = fmaxf(mt, __shfl_xor(mt, 32, 64));

        if (__any(mt > mrun + THR2)) {         // rescale path
            float mnew = fmaxf(mrun, mt);
            float alpha = __builtin_amdgcn_exp2f(mrun - mnew);
            mrun = mnew;
            lrun *= alpha;
            float al[4];
#pragma unroll
            for (int e = 0; e < 4; e++) al[e] = __shfl(alpha, g * 4 + e, 64);
#pragma unroll
            for (int df = 0; df < 4; df++)
#pragma unroll
                for (int e = 0; e < 4; e++) oacc[df][e] *= al[e];
        }

        float tsum = 0.f;
#pragma unroll
        for (int n = 0; n < 4; n++) {
            float p0 = __builtin_amdgcn_exp2f(sv[n][0] - mrun);
            float p1 = __builtin_amdgcn_exp2f(sv[n][1] - mrun);
            float p2 = __builtin_amdgcn_exp2f(sv[n][2] - mrun);
            float p3 = __builtin_amdgcn_exp2f(sv[n][3] - mrun);
            tsum += (p0 + p1) + (p2 + p3);
            f16x4 pv4;
            pv4[0] = (f16)p0; pv4[1] = (f16)p1; pv4[2] = (f16)p2; pv4[3] = (f16)p3;
            *(f16x4*)(plds[w] + ql * 80 + n * 16 + g * 4) = pv4;
        }
        tsum += __shfl_xor(tsum, 16, 64);
        tsum += __shfl_xor(tsum, 32, 64);
        lrun += tsum;

        // O += P . V
        __builtin_amdgcn_s_setprio(1);
#pragma unroll
        for (int t = 0; t < 2; t++) {
            f16x8 pf = *(const f16x8*)(plds[w] + ql * 80 + t * 32 + g * 8);
#pragma unroll
            for (int df = 0; df < 4; df++) {
                int d = df * 16 + ql;
                int u = t * 4 + g;
                f16x8 vf = *(const f16x8*)(vb + d * 64 + ((u ^ (d & 7)) * 8));
                oacc[df] = __builtin_amdgcn_mfma_f32_16x16x32_f16(pf, vf, oacc[df], 0, 0, 0);
            }
        }
        __builtin_amdgcn_s_setprio(0);
        cur ^= 1;
    }

    float linv[4];
#pragma unroll
    for (int e = 0; e < 4; e++) {
        float lv = __shfl(lrun, g * 4 + e, 64);
        linv[e] = 1.f / lv;
    }
    f16* ob = ctx + ((size_t)(b * SQ + q0 + w * 16)) * HH + h * HDIM;
#pragma unroll
    for (int df = 0; df < 4; df++)
#pragma unroll
        for (int e = 0; e < 4; e++)
            ob[(size_t)(g * 4 + e) * HH + df * 16 + ql] = (f16)(oacc[df][e] * linv[e]);
}

// ---------------------------------------------------------------------------
extern "C" void kernel_launch(void* const* d_in, const int* in_sizes, int n_in,
                              void* d_out, int out_size, void* d_ws, size_t ws_size,
                              hipStream_t stream) {
    const float* query = (const float*)d_in[0];
    const float* key   = (const float*)d_in[1];
    const float* value = (const float*)d_in[2];
    const int*   mask  = (const int*)d_in[3];
    const float* Wq = (const float*)d_in[4];
    const float* bq = (const float*)d_in[5];
    const float* Wk = (const float*)d_in[6];
    const float* bk = (const float*)d_in[7];
    const float* Wv = (const float*)d_in[8];
    const float* bv = (const float*)d_in[9];
    const float* Wo = (const float*)d_in[10];
    const float* bo = (const float*)d_in[11];
    float* out = (float*)d_out;

    const size_t M1 = 1024 * 1024;
    f16* qcast = (f16*)d_ws;            // 4M
    f16* kcast = qcast + 4 * M1;        // 8M
    f16* vcast = kcast + 8 * M1;        // 8M
    f16* wT    = vcast + 8 * M1;        // 4M (Wq,Wk,Wv,Wo transposed)
    f16* qp    = wT + 4 * M1;           // 4M
    f16* kp    = qp + 4 * M1;           // 8M
    f16* vt    = kp + 8 * M1;           // 8M  (total 44M f16 = 88MB)
    f16* ctx   = qcast;                 // alias (qcast dead after Q-GEMM)

    dim3 blk(256);

    cast3_k<<<dim3(10240), blk, 0, stream>>>(query, key, value, qcast, kcast, vcast);
    transW4_k<<<dim3(16, 16, 4), blk, 0, stream>>>(Wq, Wk, Wv, Wo, wT);

    gemm_k<1><<<dim3(512),  blk, 0, stream>>>(qcast, wT + 0 * M1, bq, qp, 4096, HH);
    gemm_k<1><<<dim3(1024), blk, 0, stream>>>(kcast, wT + 1 * M1, bk, kp, 8192, HH);
    gemm_k<2><<<dim3(1024), blk, 0, stream>>>(vcast, wT + 2 * M1, bv, vt, 8192, HH);

    attn_mfma_k<<<dim3(1024), blk, 0, stream>>>(qp, kp, vt, mask, ctx);

    gemm_k<0><<<dim3(512),  blk, 0, stream>>>(ctx, wT + 3 * M1, bo, out, 4096, HH);
}

// Round 4
// 192.890 us; speedup vs baseline: 7.6295x; 1.1615x over previous
//
#include <hip/hip_runtime.h>
#include <hip/hip_fp16.h>
#include <math.h>

#define B_ 4
#define SQ 1024
#define SK 2048
#define HH 1024
#define NHEAD 16
#define HDIM 64

typedef _Float16 f16;
typedef __attribute__((ext_vector_type(8))) _Float16 f16x8;
typedef __attribute__((ext_vector_type(4))) _Float16 f16x4;
typedef __attribute__((ext_vector_type(4))) float f32x4;
typedef unsigned int u32;
typedef unsigned long long u64;

#define GLOAD_LDS16(gp, lp) __builtin_amdgcn_global_load_lds( \
    (const __attribute__((address_space(1))) u32*)(gp),        \
    (__attribute__((address_space(3))) u32*)(lp), 16, 0, 0)

// ---------------------------------------------------------------------------
// Merged prep: [0,10240) cast q/k/v f32->f16 ; [10240,11264) transpose 4 W
// f32->f16 ; [11264,11296) pack mask bits via ballot.
// ---------------------------------------------------------------------------
__global__ __launch_bounds__(256) void prep_k(
    const float* __restrict__ q, const float* __restrict__ k,
    const float* __restrict__ v,
    const float* __restrict__ W0, const float* __restrict__ W1,
    const float* __restrict__ W2, const float* __restrict__ W3,
    const int* __restrict__ mask,
    f16* __restrict__ qo, f16* __restrict__ ko, f16* __restrict__ vo,
    f16* __restrict__ WT, u32* __restrict__ pmask)
{
    __shared__ f16 t[64 * 80];
    const int bid = blockIdx.x, tid = threadIdx.x;
    if (bid < 10240) {
        int i = bid * 256 + tid;
        const float* src; f16* dst; int j;
        if (i < 524288)       { src = q; dst = qo; j = i; }
        else if (i < 1572864) { src = k; dst = ko; j = i - 524288; }
        else                  { src = v; dst = vo; j = i - 1572864; }
        float4 a = ((const float4*)src)[(size_t)j * 2];
        float4 b = ((const float4*)src)[(size_t)j * 2 + 1];
        f16x8 o;
        o[0] = (f16)a.x; o[1] = (f16)a.y; o[2] = (f16)a.z; o[3] = (f16)a.w;
        o[4] = (f16)b.x; o[5] = (f16)b.y; o[6] = (f16)b.z; o[7] = (f16)b.w;
        *(f16x8*)(dst + (size_t)j * 8) = o;
    } else if (bid < 11264) {
        int id = bid - 10240;
        int z = id >> 8, idx = id & 255;
        const float* W = z == 0 ? W0 : z == 1 ? W1 : z == 2 ? W2 : W3;
        f16* out = WT + (size_t)z * HH * HH;
        const int r0 = (idx >> 4) * 64, c0 = (idx & 15) * 64;
#pragma unroll
        for (int p = 0; p < 4; p++) {
            int s = p * 256 + tid;
            int row = s >> 4, u = s & 15;
            float4 a = *(const float4*)(W + (size_t)(r0 + row) * HH + c0 + u * 4);
            f16x4 vv;
            vv[0] = (f16)a.x; vv[1] = (f16)a.y; vv[2] = (f16)a.z; vv[3] = (f16)a.w;
            *(f16x4*)(t + row * 80 + u * 4) = vv;
        }
        __syncthreads();
#pragma unroll
        for (int p = 0; p < 2; p++) {
            int s = p * 256 + tid;
            int n = s >> 3, u = s & 7;
            f16x8 vv;
#pragma unroll
            for (int j = 0; j < 8; j++) vv[j] = t[(u * 8 + j) * 80 + n];
            *(f16x8*)(out + (size_t)(c0 + n) * HH + r0 + u * 8) = vv;
        }
    } else {
        int j = (bid - 11264) * 256 + tid;          // 0..8191 over [B][SK]
        u64 bal = __ballot(mask[j] != 0);
        if ((tid & 63) == 0) *(u64*)(pmask + ((j >> 6) << 1)) = bal;
    }
}

// ---------------------------------------------------------------------------
// GEMM C = A[M,K] @ BT[N,K]^T + bias. 128x128 tile, BK=32, 4 waves (2x2),
// 16 MFMA + 8 ds_read_b128 per K-step, double-buffered LDS (1 barrier/iter),
// XOR-swizzled stage source + fragment reads, XCD swizzle. N = 1024.
// OUTMODE: 0 f32 row-major; 1 f16 row-major; 2 f16 V^T [B*NH][HD][SK].
// ---------------------------------------------------------------------------
template <int OUTMODE>
__global__ __launch_bounds__(256) void gemm_k(
    const f16* __restrict__ A, const f16* __restrict__ BT,
    const float* __restrict__ bias, void* __restrict__ Cout,
    int M, int K)
{
    __shared__ f16 sA[2][4096];
    __shared__ f16 sB[2][4096];
    const int tid = threadIdx.x, lane = tid & 63, w = tid >> 6;
    const int nwg = gridDim.x;
    const int swz = ((int)blockIdx.x & 7) * (nwg >> 3) + ((int)blockIdx.x >> 3);
    const int m0 = (swz >> 3) * 128;
    const int n0 = (swz & 7) * 128;
    const int wr = w >> 1, wc = w & 1;
    const int ql = lane & 15, g = lane >> 4;
    const int N = 1024;
    f32x4 acc[4][4] = {};

    auto stage = [&](int buf, int k0) {
#pragma unroll
        for (int p = 0; p < 2; p++) {
            int s = p * 256 + tid;
            int row = s >> 2, us = ((s & 3) ^ (row & 3)) * 8;
            f16* dst = &sA[buf][(p * 256 + w * 64) * 8];
            f16* dstB = &sB[buf][(p * 256 + w * 64) * 8];
            GLOAD_LDS16(A  + (size_t)(m0 + row) * K + k0 + us, dst);
            GLOAD_LDS16(BT + (size_t)(n0 + row) * K + k0 + us, dstB);
        }
    };

    stage(0, 0);
    int cur = 0;
    for (int k0 = 0; k0 < K; k0 += 32) {
        __syncthreads();                    // buf[cur] staged (vmcnt drained)
        if (k0 + 32 < K) stage(cur ^ 1, k0 + 32);
        f16x8 af[4], bf[4];
#pragma unroll
        for (int m = 0; m < 4; m++) {
            int row = wr * 64 + m * 16 + ql;
            af[m] = *(const f16x8*)(&sA[cur][row * 32 + ((g ^ (row & 3)) * 8)]);
        }
#pragma unroll
        for (int n = 0; n < 4; n++) {
            int row = wc * 64 + n * 16 + ql;
            bf[n] = *(const f16x8*)(&sB[cur][row * 32 + ((g ^ (row & 3)) * 8)]);
        }
#pragma unroll
        for (int m = 0; m < 4; m++)
#pragma unroll
            for (int n = 0; n < 4; n++)
                acc[m][n] = __builtin_amdgcn_mfma_f32_16x16x32_f16(af[m], bf[n], acc[m][n], 0, 0, 0);
        cur ^= 1;
    }

    float bv[4];
#pragma unroll
    for (int n = 0; n < 4; n++) bv[n] = bias[n0 + wc * 64 + n * 16 + ql];
#pragma unroll
    for (int m = 0; m < 4; m++) {
        int row0 = m0 + wr * 64 + m * 16 + g * 4;
#pragma unroll
        for (int n = 0; n < 4; n++) {
            int col = n0 + wc * 64 + n * 16 + ql;
            if (OUTMODE == 2) {
                int bb = row0 >> 11, kk = row0 & 2047;
                int hh = col >> 6, dd = col & 63;
                f16x4 vv;
#pragma unroll
                for (int e = 0; e < 4; e++) vv[e] = (f16)(acc[m][n][e] + bv[n]);
                *(f16x4*)((f16*)Cout + ((size_t)(bb * NHEAD + hh) * HDIM + dd) * SK + kk) = vv;
            } else if (OUTMODE == 1) {
#pragma unroll
                for (int e = 0; e < 4; e++)
                    ((f16*)Cout)[(size_t)(row0 + e) * N + col] = (f16)(acc[m][n][e] + bv[n]);
            } else {
#pragma unroll
                for (int e = 0; e < 4; e++)
                    ((float*)Cout)[(size_t)(row0 + e) * N + col] = acc[m][n][e] + bv[n];
            }
        }
    }
}

// ---------------------------------------------------------------------------
// Flash attention, f16 MFMA. 8 waves x 16 q-rows = 128 q-rows per block,
// one (b,h). KVBLK=64, double-buffered K/V staging (1 load/thread/buf),
// bitmask-in-LDS masking, log2 softmax + defer-max, XCD swizzle.
// ---------------------------------------------------------------------------
#define SC2 0.18033688f   /* 0.125 * log2(e) */
#define THR2 11.5f

__global__ __launch_bounds__(512, 6) void attn_mfma_k(
    const f16* __restrict__ qp,    // [B][SQ][H]
    const f16* __restrict__ kp,    // [B][SK][H]
    const f16* __restrict__ vt,    // [B*NH][HD][SK]
    const u32* __restrict__ pmask, // [B][SK/32] bit=1 -> keep
    f16* __restrict__ ctx)         // [B][SQ][H]
{
    // 64 consecutive flats (8 (b,h) sets = 4MB K/V) per XCD
    const int flat = ((int)blockIdx.x & 7) * 64 + ((int)blockIdx.x >> 3);
    const int qt = flat & 7, h = (flat >> 3) & 15, b = flat >> 7;
    const int q0 = qt * 128;
    const int tid = threadIdx.x, lane = tid & 63, w = tid >> 6;
    const int ql = lane & 15, g = lane >> 4;

    __shared__ f16 ks[2 * 4096];      // [buf][key64][d64], 16B-unit swz u^(key&7)
    __shared__ f16 vs[2 * 4096];      // [buf][d64][key64], 16B-unit swz u^(d&7)
    __shared__ f16 plds[8][16 * 80];  // per-wave P [q16][key64 + pad]
    __shared__ u32 smask[64];

    const f16* kbase = kp + (size_t)b * SK * HH + h * HDIM;
    const f16* vbase = vt + ((size_t)(b * NHEAD + h)) * HDIM * SK;

    if (tid < 64) smask[tid] = pmask[b * 64 + tid];

    f16x8 qf[2];
    {
        const f16* qb = qp + ((size_t)(b * SQ + q0 + w * 16 + ql)) * HH + h * HDIM + g * 8;
        qf[0] = *(const f16x8*)qb;
        qf[1] = *(const f16x8*)(qb + 32);
    }

    auto stageKV = [&](int buf, int kt) {
        int r = tid >> 3, ulg = ((tid & 7) ^ (r & 7)) * 8;
        GLOAD_LDS16(kbase + (size_t)(kt + r) * HH + ulg, ks + buf * 4096 + w * 512);
        GLOAD_LDS16(vbase + (size_t)r * SK + kt + ulg,   vs + buf * 4096 + w * 512);
    };

    f32x4 oacc[4] = {};
    float mrun = -1e30f, lrun = 0.f;

    stageKV(0, 0);
    int cur = 0;
    for (int kt = 0; kt < SK; kt += 64) {
        __syncthreads();                       // buf[cur] staged; prior reads done
        if (kt + 64 < SK) stageKV(cur ^ 1, kt + 64);
        const f16* kb = ks + cur * 4096;
        const f16* vb = vs + cur * 4096;

        // S^T = K . Q^T : sacc[n][e] = S[q=ql][key = n*16 + g*4 + e]
        f32x4 sacc[4] = {};
        __builtin_amdgcn_s_setprio(1);
#pragma unroll
        for (int n = 0; n < 4; n++) {
            int key = n * 16 + ql;
#pragma unroll
            for (int df = 0; df < 2; df++) {
                int u = df * 4 + g;
                f16x8 kf = *(const f16x8*)(kb + key * 64 + ((u ^ (key & 7)) * 8));
                sacc[n] = __builtin_amdgcn_mfma_f32_16x16x32_f16(kf, qf[df], sacc[n], 0, 0, 0);
            }
        }
        __builtin_amdgcn_s_setprio(0);

        // mask bias from bitmask: word n>>1, bit (n&1)*16 + g*4 + e
        u32 msh0 = smask[(kt >> 5)]     >> (g * 4);
        u32 msh1 = smask[(kt >> 5) + 1] >> (g * 4);

        float sv[4][4];
        float mt = -1e30f;
#pragma unroll
        for (int n = 0; n < 4; n++) {
            u32 msh = (n < 2) ? msh0 : msh1;
#pragma unroll
            for (int e = 0; e < 4; e++) {
                float bia = ((msh >> (((n & 1) << 4) + e)) & 1u) ? 0.f : -1e30f;
                float s = sacc[n][e] * SC2 + bia;
                sv[n][e] = s;
                mt = fmaxf(mt, s);
            }
        }
        mt = fmaxf(mt, __shfl_xor(mt, 16, 64));
        mt = fmaxf(mt, __shfl_xor(mt, 32, 64));

        if (__any(mt > mrun + THR2)) {         // deferred rescale
            float mnew = fmaxf(mrun, mt);
            float alpha = __builtin_amdgcn_exp2f(mrun - mnew);
            mrun = mnew;
            lrun *= alpha;
            float al[4];
#pragma unroll
            for (int e = 0; e < 4; e++) al[e] = __shfl(alpha, g * 4 + e, 64);
#pragma unroll
            for (int df = 0; df < 4; df++)
#pragma unroll
                for (int e = 0; e < 4; e++) oacc[df][e] *= al[e];
        }

        float tsum = 0.f;
#pragma unroll
        for (int n = 0; n < 4; n++) {
            float p0 = __builtin_amdgcn_exp2f(sv[n][0] - mrun);
            float p1 = __builtin_amdgcn_exp2f(sv[n][1] - mrun);
            float p2 = __builtin_amdgcn_exp2f(sv[n][2] - mrun);
            float p3 = __builtin_amdgcn_exp2f(sv[n][3] - mrun);
            tsum += (p0 + p1) + (p2 + p3);
            f16x4 pv4;
            pv4[0] = (f16)p0; pv4[1] = (f16)p1; pv4[2] = (f16)p2; pv4[3] = (f16)p3;
            *(f16x4*)(plds[w] + ql * 80 + n * 16 + g * 4) = pv4;
        }
        tsum += __shfl_xor(tsum, 16, 64);
        tsum += __shfl_xor(tsum, 32, 64);
        lrun += tsum;

        // O += P . V
        __builtin_amdgcn_s_setprio(1);
#pragma unroll
        for (int t = 0; t < 2; t++) {
            f16x8 pf = *(const f16x8*)(plds[w] + ql * 80 + t * 32 + g * 8);
#pragma unroll
            for (int df = 0; df < 4; df++) {
                int d = df * 16 + ql;
                int u = t * 4 + g;
                f16x8 vf = *(const f16x8*)(vb + d * 64 + ((u ^ (d & 7)) * 8));
                oacc[df] = __builtin_amdgcn_mfma_f32_16x16x32_f16(pf, vf, oacc[df], 0, 0, 0);
            }
        }
        __builtin_amdgcn_s_setprio(0);
        cur ^= 1;
    }

    float linv[4];
#pragma unroll
    for (int e = 0; e < 4; e++) {
        float lv = __shfl(lrun, g * 4 + e, 64);
        linv[e] = 1.f / lv;
    }
    f16* ob = ctx + ((size_t)(b * SQ + q0 + w * 16)) * HH + h * HDIM;
#pragma unroll
    for (int df = 0; df < 4; df++)
#pragma unroll
        for (int e = 0; e < 4; e++)
            ob[(size_t)(g * 4 + e) * HH + df * 16 + ql] = (f16)(oacc[df][e] * linv[e]);
}

// ---------------------------------------------------------------------------
extern "C" void kernel_launch(void* const* d_in, const int* in_sizes, int n_in,
                              void* d_out, int out_size, void* d_ws, size_t ws_size,
                              hipStream_t stream) {
    const float* query = (const float*)d_in[0];
    const float* key   = (const float*)d_in[1];
    const float* value = (const float*)d_in[2];
    const int*   mask  = (const int*)d_in[3];
    const float* Wq = (const float*)d_in[4];
    const float* bq = (const float*)d_in[5];
    const float* Wk = (const float*)d_in[6];
    const float* bk = (const float*)d_in[7];
    const float* Wv = (const float*)d_in[8];
    const float* bv = (const float*)d_in[9];
    const float* Wo = (const float*)d_in[10];
    const float* bo = (const float*)d_in[11];
    float* out = (float*)d_out;

    const size_t M1 = 1024 * 1024;
    f16* qcast = (f16*)d_ws;            // 4M
    f16* kcast = qcast + 4 * M1;        // 8M
    f16* vcast = kcast + 8 * M1;        // 8M
    f16* wT    = vcast + 8 * M1;        // 4M
    f16* qp    = wT + 4 * M1;           // 4M
    f16* kp    = qp + 4 * M1;           // 8M
    f16* vt    = kp + 8 * M1;           // 8M (total 44M f16 = 88MB)
    u32* pmask = (u32*)(vt + 8 * M1);   // 256 u32
    f16* ctx   = qcast;                 // alias (qcast dead after Q-GEMM)

    dim3 blk(256);

    prep_k<<<dim3(11296), blk, 0, stream>>>(query, key, value, Wq, Wk, Wv, Wo,
                                            mask, qcast, kcast, vcast, wT, pmask);

    gemm_k<1><<<dim3(256), blk, 0, stream>>>(qcast, wT + 0 * M1, bq, qp, 4096, HH);
    gemm_k<1><<<dim3(512), blk, 0, stream>>>(kcast, wT + 1 * M1, bk, kp, 8192, HH);
    gemm_k<2><<<dim3(512), blk, 0, stream>>>(vcast, wT + 2 * M1, bv, vt, 8192, HH);

    attn_mfma_k<<<dim3(512), dim3(512), 0, stream>>>(qp, kp, vt, pmask, ctx);

    gemm_k<0><<<dim3(256), blk, 0, stream>>>(ctx, wT + 3 * M1, bo, out, 4096, HH);
}

// Round 5
// 166.107 us; speedup vs baseline: 8.8596x; 1.1612x over previous
//
#include <hip/hip_runtime.h>
#include <hip/hip_fp16.h>
#include <math.h>

#define B_ 4
#define SQ 1024
#define SK 2048
#define HH 1024
#define NHEAD 16
#define HDIM 64

typedef _Float16 f16;
typedef __attribute__((ext_vector_type(8))) _Float16 f16x8;
typedef __attribute__((ext_vector_type(4))) _Float16 f16x4;
typedef __attribute__((ext_vector_type(4))) float f32x4;
typedef unsigned int u32;

#define GLOAD_LDS16(gp, lp) __builtin_amdgcn_global_load_lds( \
    (const __attribute__((address_space(1))) u32*)(gp),        \
    (__attribute__((address_space(3))) u32*)(lp), 16, 0, 0)
#define GLOAD_LDS4(gp, lp) __builtin_amdgcn_global_load_lds(  \
    (const __attribute__((address_space(1))) u32*)(gp),        \
    (__attribute__((address_space(3))) u32*)(lp), 4, 0, 0)

// ---------------------------------------------------------------------------
// Merged prep: [0,10240) cast q/k/v f32->f16 ; [10240,11264) transpose 4 W
// f32->f16 ; [11264,11296) mask -> f32 bias row (0 / -1e30).
// ---------------------------------------------------------------------------
__global__ __launch_bounds__(256) void prep_k(
    const float* __restrict__ q, const float* __restrict__ k,
    const float* __restrict__ v,
    const float* __restrict__ W0, const float* __restrict__ W1,
    const float* __restrict__ W2, const float* __restrict__ W3,
    const int* __restrict__ mask,
    f16* __restrict__ qo, f16* __restrict__ ko, f16* __restrict__ vo,
    f16* __restrict__ WT, float* __restrict__ pbias)
{
    __shared__ f16 t[64 * 80];
    const int bid = blockIdx.x, tid = threadIdx.x;
    if (bid < 10240) {
        int i = bid * 256 + tid;
        const float* src; f16* dst; int j;
        if (i < 524288)       { src = q; dst = qo; j = i; }
        else if (i < 1572864) { src = k; dst = ko; j = i - 524288; }
        else                  { src = v; dst = vo; j = i - 1572864; }
        float4 a = ((const float4*)src)[(size_t)j * 2];
        float4 b = ((const float4*)src)[(size_t)j * 2 + 1];
        f16x8 o;
        o[0] = (f16)a.x; o[1] = (f16)a.y; o[2] = (f16)a.z; o[3] = (f16)a.w;
        o[4] = (f16)b.x; o[5] = (f16)b.y; o[6] = (f16)b.z; o[7] = (f16)b.w;
        *(f16x8*)(dst + (size_t)j * 8) = o;
    } else if (bid < 11264) {
        int id = bid - 10240;
        int z = id >> 8, idx = id & 255;
        const float* W = z == 0 ? W0 : z == 1 ? W1 : z == 2 ? W2 : W3;
        f16* out = WT + (size_t)z * HH * HH;
        const int r0 = (idx >> 4) * 64, c0 = (idx & 15) * 64;
#pragma unroll
        for (int p = 0; p < 4; p++) {
            int s = p * 256 + tid;
            int row = s >> 4, u = s & 15;
            float4 a = *(const float4*)(W + (size_t)(r0 + row) * HH + c0 + u * 4);
            f16x4 vv;
            vv[0] = (f16)a.x; vv[1] = (f16)a.y; vv[2] = (f16)a.z; vv[3] = (f16)a.w;
            *(f16x4*)(t + row * 80 + u * 4) = vv;
        }
        __syncthreads();
#pragma unroll
        for (int p = 0; p < 2; p++) {
            int s = p * 256 + tid;
            int n = s >> 3, u = s & 7;
            f16x8 vv;
#pragma unroll
            for (int j = 0; j < 8; j++) vv[j] = t[(u * 8 + j) * 80 + n];
            *(f16x8*)(out + (size_t)(c0 + n) * HH + r0 + u * 8) = vv;
        }
    } else {
        int j = (bid - 11264) * 256 + tid;          // 0..8191 over [B][SK]
        pbias[j] = mask[j] ? 0.f : -1e30f;
    }
}

// ---------------------------------------------------------------------------
// GEMM body: C = A[M,K] @ BT[1024,K]^T + bias. Tile TM x 128, BK=32,
// 4 waves (2x2), double-buffered LDS (1 barrier/iter), 2-way-free XOR
// swizzle x(row)=(row>>1)&3 on stage source + fragment reads, XCD swizzle.
// OUTMODE: 0 f32 row-major; 1 f16 row-major; 2 f16 V^T [B*NH][HD][SK].
// ---------------------------------------------------------------------------
template <int TM, int OUTMODE>
__device__ __forceinline__ void gemm_body(
    const f16* __restrict__ A, const f16* __restrict__ BT,
    const float* __restrict__ bias, void* __restrict__ Cout,
    int M, int bid, int nwg, f16* sA, f16* sB)
{
    const int tid = threadIdx.x, lane = tid & 63, w = tid >> 6;
    const int swz = (bid & 7) * (nwg >> 3) + (bid >> 3);
    const int m0 = (swz >> 3) * TM;
    const int n0 = (swz & 7) * 128;
    const int wr = w >> 1, wc = w & 1;
    const int ql = lane & 15, g = lane >> 4;
    const int N = 1024, K = 1024;
    const int MF = TM / 32;                     // m-frags per wave (2 or 4)
    const int ABUF = TM * 32;                   // f16 per A buffer
    f32x4 acc[TM / 32][4] = {};

    auto stage = [&](int buf, int k0) {
#pragma unroll
        for (int p = 0; p < TM / 64; p++) {     // A: TM*4 slots
            int s = p * 256 + tid;
            int row = s >> 2, us = ((s & 3) ^ ((row >> 1) & 3)) * 8;
            GLOAD_LDS16(A + (size_t)(m0 + row) * K + k0 + us,
                        sA + buf * ABUF + (p * 256 + w * 64) * 8);
        }
#pragma unroll
        for (int p = 0; p < 2; p++) {           // B: 512 slots
            int s = p * 256 + tid;
            int row = s >> 2, us = ((s & 3) ^ ((row >> 1) & 3)) * 8;
            GLOAD_LDS16(BT + (size_t)(n0 + row) * K + k0 + us,
                        sB + buf * 4096 + (p * 256 + w * 64) * 8);
        }
    };

    stage(0, 0);
    int cur = 0;
    for (int k0 = 0; k0 < K; k0 += 32) {
        __syncthreads();                        // buf[cur] staged (vmcnt drained)
        if (k0 + 32 < K) stage(cur ^ 1, k0 + 32);
        f16x8 af[MF], bf[4];
#pragma unroll
        for (int m = 0; m < MF; m++) {
            int row = wr * (TM / 2) + m * 16 + ql;
            af[m] = *(const f16x8*)(sA + cur * ABUF + row * 32 + ((g ^ ((row >> 1) & 3)) * 8));
        }
#pragma unroll
        for (int n = 0; n < 4; n++) {
            int row = wc * 64 + n * 16 + ql;
            bf[n] = *(const f16x8*)(sB + cur * 4096 + row * 32 + ((g ^ ((row >> 1) & 3)) * 8));
        }
#pragma unroll
        for (int m = 0; m < MF; m++)
#pragma unroll
            for (int n = 0; n < 4; n++)
                acc[m][n] = __builtin_amdgcn_mfma_f32_16x16x32_f16(af[m], bf[n], acc[m][n], 0, 0, 0);
        cur ^= 1;
    }

    float bv[4];
#pragma unroll
    for (int n = 0; n < 4; n++) bv[n] = bias[n0 + wc * 64 + n * 16 + ql];
#pragma unroll
    for (int m = 0; m < MF; m++) {
        int row0 = m0 + wr * (TM / 2) + m * 16 + g * 4;
#pragma unroll
        for (int n = 0; n < 4; n++) {
            int col = n0 + wc * 64 + n * 16 + ql;
            if (OUTMODE == 2) {
                int bb = row0 >> 11, kk = row0 & 2047;
                int hh = col >> 6, dd = col & 63;
                f16x4 vv;
#pragma unroll
                for (int e = 0; e < 4; e++) vv[e] = (f16)(acc[m][n][e] + bv[n]);
                *(f16x4*)((f16*)Cout + ((size_t)(bb * NHEAD + hh) * HDIM + dd) * SK + kk) = vv;
            } else if (OUTMODE == 1) {
#pragma unroll
                for (int e = 0; e < 4; e++)
                    ((f16*)Cout)[(size_t)(row0 + e) * N + col] = (f16)(acc[m][n][e] + bv[n]);
            } else {
#pragma unroll
                for (int e = 0; e < 4; e++)
                    ((float*)Cout)[(size_t)(row0 + e) * N + col] = acc[m][n][e] + bv[n];
            }
        }
    }
}

// Merged Q/K/V projection launch: [0,512) Q (64-tile), [512,1024) K (128),
// [1024,1536) V (128, V^T epilogue).
__global__ __launch_bounds__(256) void qkv_gemm_k(
    const f16* __restrict__ qc, const f16* __restrict__ kc,
    const f16* __restrict__ vc, const f16* __restrict__ wT,
    const float* __restrict__ bq, const float* __restrict__ bk,
    const float* __restrict__ bv,
    f16* __restrict__ qp, f16* __restrict__ kp, f16* __restrict__ vt)
{
    __shared__ f16 sA[2 * 4096];
    __shared__ f16 sB[2 * 4096];
    const int bid = blockIdx.x;
    const size_t M1 = 1024 * 1024;
    if (bid < 512)
        gemm_body<64, 1>(qc, wT, bq, qp, 4096, bid, 512, sA, sB);
    else if (bid < 1024)
        gemm_body<128, 1>(kc, wT + M1, bk, kp, 8192, bid - 512, 512, sA, sB);
    else
        gemm_body<128, 2>(vc, wT + 2 * M1, bv, vt, 8192, bid - 1024, 512, sA, sB);
}

__global__ __launch_bounds__(256) void o_gemm_k(
    const f16* __restrict__ ctx, const f16* __restrict__ wT,
    const float* __restrict__ bo, float* __restrict__ out)
{
    __shared__ f16 sA[2 * 4096];
    __shared__ f16 sB[2 * 4096];
    gemm_body<64, 0>(ctx, wT, bo, out, 4096, blockIdx.x, 512, sA, sB);
}

// ---------------------------------------------------------------------------
// Flash attention, f16 MFMA. 8 waves x 16 q-rows = 128 q-rows per block,
// one (b,h). KVBLK=64, double-buffered K/V + bias staging (1 barrier/tile),
// f32 bias row via global_load_lds size-4, log2 softmax + defer-max,
// XCD swizzle. LDS 53.8KB -> 2 blocks/CU.
// ---------------------------------------------------------------------------
#define SC2 0.18033688f   /* 0.125 * log2(e) */
#define THR2 11.5f

__global__ __launch_bounds__(512, 6) void attn_mfma_k(
    const f16* __restrict__ qp,     // [B][SQ][H]
    const f16* __restrict__ kp,     // [B][SK][H]
    const f16* __restrict__ vt,     // [B*NH][HD][SK]
    const float* __restrict__ pbias,// [B][SK] 0 / -1e30
    f16* __restrict__ ctx)          // [B][SQ][H]
{
    // 64 consecutive flats (8 (b,h) sets = 4MB K/V) per XCD
    const int flat = ((int)blockIdx.x & 7) * 64 + ((int)blockIdx.x >> 3);
    const int qt = flat & 7, h = (flat >> 3) & 15, b = flat >> 7;
    const int q0 = qt * 128;
    const int tid = threadIdx.x, lane = tid & 63, w = tid >> 6;
    const int ql = lane & 15, g = lane >> 4;

    __shared__ f16 ks[2 * 4096];      // [buf][key64][d64], 16B-unit swz u^(key&7)
    __shared__ f16 vs[2 * 4096];      // [buf][d64][key64], 16B-unit swz u^(d&7)
    __shared__ f16 plds[8][16 * 80];  // per-wave P [q16][key64 + pad]
    __shared__ float sbias[2][64];

    const f16* kbase = kp + (size_t)b * SK * HH + h * HDIM;
    const f16* vbase = vt + ((size_t)(b * NHEAD + h)) * HDIM * SK;
    const float* bbase = pbias + b * SK;

    f16x8 qf[2];
    {
        const f16* qb = qp + ((size_t)(b * SQ + q0 + w * 16 + ql)) * HH + h * HDIM + g * 8;
        qf[0] = *(const f16x8*)qb;
        qf[1] = *(const f16x8*)(qb + 32);
    }

    auto stageKV = [&](int buf, int kt) {
        int r = tid >> 3, ulg = ((tid & 7) ^ (r & 7)) * 8;
        GLOAD_LDS16(kbase + (size_t)(kt + r) * HH + ulg, ks + buf * 4096 + w * 512);
        GLOAD_LDS16(vbase + (size_t)r * SK + kt + ulg,   vs + buf * 4096 + w * 512);
        if (w == 0) GLOAD_LDS4(bbase + kt + lane, &sbias[buf][0]);
    };

    f32x4 oacc[4] = {};
    float mrun = -1e30f, lrun = 0.f;

    stageKV(0, 0);
    int cur = 0;
    for (int kt = 0; kt < SK; kt += 64) {
        __syncthreads();                       // buf[cur] staged; prior reads done
        if (kt + 64 < SK) stageKV(cur ^ 1, kt + 64);
        const f16* kb = ks + cur * 4096;
        const f16* vb = vs + cur * 4096;

        // S^T = K . Q^T : sacc[n][e] = S[q=ql][key = n*16 + g*4 + e]
        f32x4 sacc[4] = {};
        __builtin_amdgcn_s_setprio(1);
#pragma unroll
        for (int n = 0; n < 4; n++) {
            int key = n * 16 + ql;
#pragma unroll
            for (int df = 0; df < 2; df++) {
                int u = df * 4 + g;
                f16x8 kf = *(const f16x8*)(kb + key * 64 + ((u ^ (key & 7)) * 8));
                sacc[n] = __builtin_amdgcn_mfma_f32_16x16x32_f16(kf, qf[df], sacc[n], 0, 0, 0);
            }
        }
        __builtin_amdgcn_s_setprio(0);

        float sv[4][4];
        float mt = -1e30f;
#pragma unroll
        for (int n = 0; n < 4; n++) {
            float4 b4 = *(const float4*)&sbias[cur][n * 16 + g * 4];
            float barr[4] = {b4.x, b4.y, b4.z, b4.w};
#pragma unroll
            for (int e = 0; e < 4; e++) {
                float s = fmaf(sacc[n][e], SC2, barr[e]);
                sv[n][e] = s;
                mt = fmaxf(mt, s);
            }
        }
        mt = fmaxf(mt, __shfl_xor(mt, 16, 64));
        mt = fmaxf(mt, __shfl_xor(mt, 32, 64));

        if (__any(mt > mrun + THR2)) {         // deferred rescale
            float mnew = fmaxf(mrun, mt);
            float alpha = __builtin_amdgcn_exp2f(mrun - mnew);
            mrun = mnew;
            lrun *= alpha;
            float al[4];
#pragma unroll
            for (int e = 0; e < 4; e++) al[e] = __shfl(alpha, g * 4 + e, 64);
#pragma unroll
            for (int df = 0; df < 4; df++)
#pragma unroll
                for (int e = 0; e < 4; e++) oacc[df][e] *= al[e];
        }

        float tsum = 0.f;
#pragma unroll
        for (int n = 0; n < 4; n++) {
            float p0 = __builtin_amdgcn_exp2f(sv[n][0] - mrun);
            float p1 = __builtin_amdgcn_exp2f(sv[n][1] - mrun);
            float p2 = __builtin_amdgcn_exp2f(sv[n][2] - mrun);
            float p3 = __builtin_amdgcn_exp2f(sv[n][3] - mrun);
            tsum += (p0 + p1) + (p2 + p3);
            f16x4 pv4;
            pv4[0] = (f16)p0; pv4[1] = (f16)p1; pv4[2] = (f16)p2; pv4[3] = (f16)p3;
            *(f16x4*)(plds[w] + ql * 80 + n * 16 + g * 4) = pv4;
        }
        tsum += __shfl_xor(tsum, 16, 64);
        tsum += __shfl_xor(tsum, 32, 64);
        lrun += tsum;

        // O += P . V
        __builtin_amdgcn_s_setprio(1);
#pragma unroll
        for (int t = 0; t < 2; t++) {
            f16x8 pf = *(const f16x8*)(plds[w] + ql * 80 + t * 32 + g * 8);
#pragma unroll
            for (int df = 0; df < 4; df++) {
                int d = df * 16 + ql;
                int u = t * 4 + g;
                f16x8 vf = *(const f16x8*)(vb + d * 64 + ((u ^ (d & 7)) * 8));
                oacc[df] = __builtin_amdgcn_mfma_f32_16x16x32_f16(pf, vf, oacc[df], 0, 0, 0);
            }
        }
        __builtin_amdgcn_s_setprio(0);
        cur ^= 1;
    }

    float linv[4];
#pragma unroll
    for (int e = 0; e < 4; e++) {
        float lv = __shfl(lrun, g * 4 + e, 64);
        linv[e] = 1.f / lv;
    }
    f16* ob = ctx + ((size_t)(b * SQ + q0 + w * 16)) * HH + h * HDIM;
#pragma unroll
    for (int df = 0; df < 4; df++)
#pragma unroll
        for (int e = 0; e < 4; e++)
            ob[(size_t)(g * 4 + e) * HH + df * 16 + ql] = (f16)(oacc[df][e] * linv[e]);
}

// ---------------------------------------------------------------------------
extern "C" void kernel_launch(void* const* d_in, const int* in_sizes, int n_in,
                              void* d_out, int out_size, void* d_ws, size_t ws_size,
                              hipStream_t stream) {
    const float* query = (const float*)d_in[0];
    const float* key   = (const float*)d_in[1];
    const float* value = (const float*)d_in[2];
    const int*   mask  = (const int*)d_in[3];
    const float* Wq = (const float*)d_in[4];
    const float* bq = (const float*)d_in[5];
    const float* Wk = (const float*)d_in[6];
    const float* bk = (const float*)d_in[7];
    const float* Wv = (const float*)d_in[8];
    const float* bv = (const float*)d_in[9];
    const float* Wo = (const float*)d_in[10];
    const float* bo = (const float*)d_in[11];
    float* out = (float*)d_out;

    const size_t M1 = 1024 * 1024;
    f16* qcast = (f16*)d_ws;            // 4M
    f16* kcast = qcast + 4 * M1;        // 8M
    f16* vcast = kcast + 8 * M1;        // 8M
    f16* wT    = vcast + 8 * M1;        // 4M
    f16* qp    = wT + 4 * M1;           // 4M
    f16* kp    = qp + 4 * M1;           // 8M
    f16* vt    = kp + 8 * M1;           // 8M (total 44M f16 = 88MB)
    float* pbias = (float*)(vt + 8 * M1); // 8192 f32 = 32KB
    f16* ctx   = qcast;                 // alias (qcast dead after Q-GEMM)

    dim3 blk(256);

    prep_k<<<dim3(11296), blk, 0, stream>>>(query, key, value, Wq, Wk, Wv, Wo,
                                            mask, qcast, kcast, vcast, wT, pbias);

    qkv_gemm_k<<<dim3(1536), blk, 0, stream>>>(qcast, kcast, vcast, wT,
                                               bq, bk, bv, qp, kp, vt);

    attn_mfma_k<<<dim3(512), dim3(512), 0, stream>>>(qp, kp, vt, pbias, ctx);

    o_gemm_k<<<dim3(512), blk, 0, stream>>>(ctx, wT + 3 * M1, bo, out);
}